// Round 4
// baseline (169.821 us; speedup 1.0000x reference)
//
#include <hip/hip_runtime.h>
#include <math.h>

#define BB 8
#define TT 96
#define SS 192
#define DIN 512
#define DM 512

typedef short short8 __attribute__((ext_vector_type(8)));
typedef float f32x4 __attribute__((ext_vector_type(4)));

__device__ __forceinline__ unsigned short f2bf(float f) {
    unsigned int u = __float_as_uint(f);
    unsigned int r = u + 0x7FFFu + ((u >> 16) & 1u);   // RNE
    return (unsigned short)(r >> 16);
}
__device__ __forceinline__ float bf2f(unsigned short h) {
    return __uint_as_float(((unsigned int)h) << 16);
}

// pack 2 fp32 -> 2 bf16 (RNE), pure software path (element-independent:
// proven correct in round 3; the HW v_cvt_pk asm failed correctness in round 1)
__device__ __forceinline__ unsigned int pack2bf(float lo, float hi) {
    return ((unsigned int)f2bf(hi) << 16) | (unsigned int)f2bf(lo);
}

// load 8 consecutive fp32 and convert to a bf16x8 MFMA fragment (k-ascending)
__device__ __forceinline__ short8 load_cvt8(const float* __restrict__ p) {
    float4 a = *(const float4*)p;
    float4 b = *(const float4*)(p + 4);
    union { unsigned int u[4]; short8 s; } r;
    r.u[0] = pack2bf(a.x, a.y);
    r.u[1] = pack2bf(a.z, a.w);
    r.u[2] = pack2bf(b.x, b.y);
    r.u[3] = pack2bf(b.z, b.w);
    return r.s;
}

// ---------------- 16x32 wave-tile GEMM: out = A @ W^T (+bias) ----------------
// LDS-free, barrier-free. A [M][lda] fp32, W rows [n][ldw] fp32, K=512.
// Proven layout: A-frag lane(mrow) row / octet quad; B-frag lane(mrow)=out col;
// C/D: col=lane&15, row=quad*4+rg.
__device__ __forceinline__ void wave_gemm16x32(
    const float* __restrict__ A, int lda,
    const float* __restrict__ W, int ldw,
    const float* __restrict__ bias, int wr, int wc,
    unsigned short* __restrict__ outB, float* __restrict__ outF)
{
    const int lane = threadIdx.x & 63;
    const int quad = lane >> 4, mrow = lane & 15;
    const float* arow = A + (size_t)(wr * 16 + mrow) * lda + quad * 8;
    const float* w0   = W + (size_t)(wc * 32 + mrow) * ldw + quad * 8;
    const float* w1   = w0 + (size_t)16 * ldw;

    f32x4 acc0 = {0,0,0,0}, acc1 = {0,0,0,0};
    #pragma unroll 4
    for (int c = 0; c < 16; ++c) {          // K = 512 = 16 x 32
        short8 av = load_cvt8(arow + c * 32);
        short8 b0 = load_cvt8(w0 + c * 32);
        short8 b1 = load_cvt8(w1 + c * 32);
        acc0 = __builtin_amdgcn_mfma_f32_16x16x32_bf16(av, b0, acc0, 0, 0, 0);
        acc1 = __builtin_amdgcn_mfma_f32_16x16x32_bf16(av, b1, acc1, 0, 0, 0);
    }

    f32x4 accs[2] = {acc0, acc1};
    #pragma unroll
    for (int ct = 0; ct < 2; ++ct) {
        int col = wc * 32 + ct * 16 + mrow;
        float bv = bias ? bias[col] : 0.0f;
        #pragma unroll
        for (int rg = 0; rg < 4; ++rg) {
            int rw = wr * 16 + quad * 4 + rg;
            float val = accs[ct][rg] + bv;
            if (outF) outF[(size_t)rw * DM + col] = val;
            else      outB[(size_t)rw * DM + col] = f2bf(val);
        }
    }
}

// ---------------- fused projections: 4 segments, 4608 waves = 1152 blocks ----
// [0,768):    wq = inputs @ Wq^T                     -> bf16 [768][512]
// [768,2304): uh = mems @ Wc^T + bc                  -> bf16 [1536][512]
// [2304,3840):M2 = mems @ WoutC^T  (Wout cols 0:512) -> bf16 [1536][512]
// [3840,4608):ih = inputs @ WoutI^T + bout (cols 512:1024) -> fp32 [768][512]
__global__ __launch_bounds__(256) void proj_gemm(
    const float* __restrict__ inputs, const float* __restrict__ mems,
    const float* __restrict__ Wq, const float* __restrict__ Wc,
    const float* __restrict__ bc,
    const float* __restrict__ Wout, const float* __restrict__ bout,
    unsigned short* __restrict__ wq_o, unsigned short* __restrict__ uh_o,
    unsigned short* __restrict__ m2_o, float* __restrict__ ih_o)
{
    int id = blockIdx.x * 4 + (threadIdx.x >> 6);
    if (id < 768) {
        wave_gemm16x32(inputs, DIN, Wq, DIN, nullptr, id >> 4, id & 15,
                       wq_o, nullptr);
    } else if (id < 2304) {
        id -= 768;
        wave_gemm16x32(mems, DM, Wc, DM, bc, id >> 4, id & 15,
                       uh_o, nullptr);
    } else if (id < 3840) {
        id -= 2304;
        wave_gemm16x32(mems, DM, Wout, DM + DIN, nullptr, id >> 4, id & 15,
                       m2_o, nullptr);
    } else {
        id -= 3840;
        wave_gemm16x32(inputs, DIN, Wout + DM, DM + DIN, bout, id >> 4, id & 15,
                       nullptr, ih_o);
    }
}

// ---------------- fused scores + softmax + context(M2) + ih add -------------
// one block per (b,t). Scores: wave wid owns s = wid,wid+4,... (proven path).
// Context: attn_h[row] = inv * sum_s e_s * M2[b,s,:] + ih[row,:]
//   wave wid owns s in [wid*48,(wid+1)*48); lane owns dims lane*8..+8
//   -> 48 independent coalesced 1KB row loads per wave (latency pipelined),
//      LDS cross-wave reduce. Replaces the 192-iteration serial walk (41 us).
__global__ __launch_bounds__(256) void attn_core(
    const unsigned short* __restrict__ wq,     // [B*T][DM] bf16
    const unsigned short* __restrict__ uh,     // [B*S][DM] bf16
    const float* __restrict__ v,               // [DM] fp32
    const unsigned short* __restrict__ m2,     // [B*S][DM] bf16
    const float* __restrict__ ih,              // [B*T][DIN] fp32 (incl bout)
    const int* __restrict__ masks,             // [B]
    float* __restrict__ align_out,             // [B*T][S] fp32
    float* __restrict__ attn_h)                // [B*T][DIN] fp32
{
    __shared__ float s_align[SS];
    __shared__ __align__(16) float s_part[4][DM];
    __shared__ float s_stat;
    const int row = blockIdx.x, b = row / TT;
    const int tid = threadIdx.x, lane = tid & 63, wid = tid >> 6;
    const int len = masks[b];

    float qf[8], vf[8];
    {
        short8 q = *(const short8*)(wq + (size_t)row * DM + lane * 8);
        float4 v0 = *(const float4*)(v + lane * 8);
        float4 v1 = *(const float4*)(v + lane * 8 + 4);
        #pragma unroll
        for (int j = 0; j < 8; ++j) qf[j] = bf2f((unsigned short)q[j]);
        vf[0] = v0.x; vf[1] = v0.y; vf[2] = v0.z; vf[3] = v0.w;
        vf[4] = v1.x; vf[5] = v1.y; vf[6] = v1.z; vf[7] = v1.w;
    }

    for (int s = wid; s < SS; s += 4) {
        float val = -INFINITY;
        if (s < len) {
            short8 u = *(const short8*)(uh + ((size_t)b * SS + s) * DM + lane * 8);
            float part = 0.f;
            #pragma unroll
            for (int j = 0; j < 8; ++j) {
                float x = qf[j] + bf2f((unsigned short)u[j]);
                // exact tanh: 1 - 2/(exp2(x*2/ln2)+1)
                float e = __builtin_amdgcn_exp2f(x * 2.885390082f);
                float th = fmaf(-2.f, __builtin_amdgcn_rcpf(e + 1.f), 1.f);
                part = fmaf(vf[j], th, part);
            }
            #pragma unroll
            for (int off = 32; off; off >>= 1)
                part += __shfl_xor(part, off);
            val = part;
        }
        if (lane == 0) s_align[s] = val;
    }
    __syncthreads();

    if (tid < 64) {
        float m = fmaxf(fmaxf(s_align[tid], s_align[tid + 64]), s_align[tid + 128]);
        #pragma unroll
        for (int off = 32; off; off >>= 1) m = fmaxf(m, __shfl_xor(m, off));
        float e0 = __builtin_amdgcn_exp2f((s_align[tid]       - m) * 1.44269504f);
        float e1 = __builtin_amdgcn_exp2f((s_align[tid + 64]  - m) * 1.44269504f);
        float e2 = __builtin_amdgcn_exp2f((s_align[tid + 128] - m) * 1.44269504f);
        s_align[tid] = e0; s_align[tid + 64] = e1; s_align[tid + 128] = e2;
        float sum = e0 + e1 + e2;
        #pragma unroll
        for (int off = 32; off; off >>= 1) sum += __shfl_xor(sum, off);
        if (tid == 0) s_stat = 1.0f / sum;
    }
    __syncthreads();
    const float inv = s_stat;
    if (tid < SS) align_out[(size_t)row * SS + tid] = s_align[tid] * inv;

    // ---- context partials: wave wid covers s in [wid*48, wid*48+48) ----
    float accv[8] = {0,0,0,0,0,0,0,0};
    const unsigned short* m2b = m2 + ((size_t)b * SS + wid * 48) * DM + lane * 8;
    #pragma unroll 8
    for (int i = 0; i < 48; ++i) {
        float p = s_align[wid * 48 + i];           // e_s (0 for masked s)
        short8 mv = *(const short8*)(m2b + (size_t)i * DM);
        #pragma unroll
        for (int j = 0; j < 8; ++j)
            accv[j] = fmaf(p, bf2f((unsigned short)mv[j]), accv[j]);
    }
    {
        float4 t0; t0.x = accv[0]; t0.y = accv[1]; t0.z = accv[2]; t0.w = accv[3];
        float4 t1; t1.x = accv[4]; t1.y = accv[5]; t1.z = accv[6]; t1.w = accv[7];
        *(float4*)&s_part[wid][lane * 8]     = t0;
        *(float4*)&s_part[wid][lane * 8 + 4] = t1;
    }
    __syncthreads();

    // ---- cross-wave reduce + ih add: thread owns dims 2*tid, 2*tid+1 ----
    const int d0 = tid * 2;
    float r0 = s_part[0][d0]     + s_part[1][d0]     + s_part[2][d0]     + s_part[3][d0];
    float r1 = s_part[0][d0 + 1] + s_part[1][d0 + 1] + s_part[2][d0 + 1] + s_part[3][d0 + 1];
    float2 ihv = *(const float2*)(ih + (size_t)row * DIN + d0);
    float2 o;
    o.x = fmaf(r0, inv, ihv.x);
    o.y = fmaf(r1, inv, ihv.y);
    *(float2*)(attn_h + (size_t)row * DIN + d0) = o;
}

extern "C" void kernel_launch(void* const* d_in, const int* in_sizes, int n_in,
                              void* d_out, int out_size, void* d_ws, size_t ws_size,
                              hipStream_t stream) {
    (void)in_sizes; (void)n_in; (void)out_size; (void)ws_size;
    const float* inputs = (const float*)d_in[0];
    const float* mems   = (const float*)d_in[1];
    const int*   masks  = (const int*)  d_in[2];
    const float* Wq     = (const float*)d_in[3];
    const float* Wc     = (const float*)d_in[4];
    const float* bc     = (const float*)d_in[5];
    const float* v      = (const float*)d_in[6];
    const float* Wout   = (const float*)d_in[7];
    const float* bout   = (const float*)d_in[8];

    unsigned short* p = (unsigned short*)d_ws;
    unsigned short* uh_bf = p;            p += 786432;   // [B*S][DM] bf16
    unsigned short* wq_bf = p;            p += 393216;   // [B*T][DM] bf16
    unsigned short* m2_bf = p;            p += 786432;   // [B*S][DM] bf16
    float* ih             = (float*)p;                   // [B*T][DIN] fp32 (16B-aligned)

    float* attn_h    = (float*)d_out;                    // [768][512]
    float* align_out = attn_h + (size_t)BB * TT * DIN;   // [768][192]

    proj_gemm<<<1152, 256, 0, stream>>>(inputs, mems, Wq, Wc, bc, Wout, bout,
                                        wq_bf, uh_bf, m2_bf, ih);
    attn_core<<<BB * TT, 256, 0, stream>>>(wq_bf, uh_bf, v, m2_bf, ih, masks,
                                           align_out, attn_h);
}

// Round 5
// 119.399 us; speedup vs baseline: 1.4223x; 1.4223x over previous
//
#include <hip/hip_runtime.h>
#include <math.h>

#define BB 8
#define TT 96
#define SS 192
#define DIN 512
#define DM 512

typedef short short8 __attribute__((ext_vector_type(8)));
typedef float f32x4 __attribute__((ext_vector_type(4)));

__device__ __forceinline__ unsigned short f2bf(float f) {
    unsigned int u = __float_as_uint(f);
    unsigned int r = u + 0x7FFFu + ((u >> 16) & 1u);   // RNE
    return (unsigned short)(r >> 16);
}
__device__ __forceinline__ float bf2f(unsigned short h) {
    return __uint_as_float(((unsigned int)h) << 16);
}

__device__ __forceinline__ void load_lds16(const void* g, void* l) {
    __builtin_amdgcn_global_load_lds((__attribute__((address_space(1))) void*)g,
                                     (__attribute__((address_space(3))) void*)l,
                                     16, 0, 0);
}

// ---------------- prep: fp32 -> bf16 conversion of 5 arrays ----------------
// sizes: inputs 393216, mems 786432, Wq 262144, Wc 262144, Wout 524288
// blocks (2048 elems each): 192, 384, 128, 128, 256 ; cum 192,576,704,832,1088
__global__ __launch_bounds__(256) void prep_cvt(
    const float* __restrict__ s0, const float* __restrict__ s1,
    const float* __restrict__ s2, const float* __restrict__ s3,
    const float* __restrict__ s4,
    unsigned short* __restrict__ d0, unsigned short* __restrict__ d1,
    unsigned short* __restrict__ d2, unsigned short* __restrict__ d3,
    unsigned short* __restrict__ d4)
{
    int bid = blockIdx.x;
    const float* s; unsigned short* d; int base;
    if (bid < 192)      { s = s0; d = d0; base = bid * 2048; }
    else if (bid < 576) { s = s1; d = d1; base = (bid - 192) * 2048; }
    else if (bid < 704) { s = s2; d = d2; base = (bid - 576) * 2048; }
    else if (bid < 832) { s = s3; d = d3; base = (bid - 704) * 2048; }
    else                { s = s4; d = d4; base = (bid - 832) * 2048; }
    int idx = base + threadIdx.x * 8;
    float4 a = *(const float4*)(s + idx);
    float4 b = *(const float4*)(s + idx + 4);
    short8 o;
    o[0] = (short)f2bf(a.x); o[1] = (short)f2bf(a.y);
    o[2] = (short)f2bf(a.z); o[3] = (short)f2bf(a.w);
    o[4] = (short)f2bf(b.x); o[5] = (short)f2bf(b.y);
    o[6] = (short)f2bf(b.z); o[7] = (short)f2bf(b.w);
    *(short8*)(d + idx) = o;
}

// ---------------- bf16 MFMA GEMM tile (round-0 proven structure) ------------
// out[m][n] = sum_k A[m][k]*W[n][k] ; 64x64 tile, 256 threads (4 waves),
// K-chunk 32, double-buffered LDS via global_load_lds width=16.
// lda/ldw row strides (W may be a column sub-block of Wout, ldw=1024).
__device__ __forceinline__ void gemm_tile(
    unsigned short* As, unsigned short* Ws,   // shared, 2*2048 ushorts each
    const unsigned short* __restrict__ A, int lda,
    const unsigned short* __restrict__ W, int ldw,
    const float* __restrict__ bias,
    float* __restrict__ outF, unsigned short* __restrict__ outB,
    int bm, int bn, int N, int K)
{
    const int tid = threadIdx.x;
    const int r  = tid >> 2;          // 0..63 : tile row loaded by this thread
    const int kc = (tid & 3) * 8;     // k-offset within chunk
    const int lane = tid & 63, wv = tid >> 6;
    const int quad = lane >> 4, mrow = lane & 15;

    f32x4 acc0 = {0,0,0,0}, acc1 = {0,0,0,0}, acc2 = {0,0,0,0}, acc3 = {0,0,0,0};

    const unsigned short* arow = A + (size_t)(bm + r) * lda;
    const unsigned short* wrow = W + (size_t)(bn + r) * ldw;

    load_lds16(arow + kc, As + tid * 8);
    load_lds16(wrow + kc, Ws + tid * 8);
    __syncthreads();

    const int NC = K >> 5;
    for (int c = 0; c < NC; ++c) {
        const int cur = (c & 1) * 2048;
        if (c + 1 < NC) {
            const int nxt = 2048 - cur;
            int gk = ((c + 1) << 5) + kc;
            load_lds16(arow + gk, As + nxt + tid * 8);
            load_lds16(wrow + gk, Ws + nxt + tid * 8);
        }
        short8 av = *(const short8*)(As + cur + (wv * 16 + mrow) * 32 + quad * 8);
        short8 b0 = *(const short8*)(Ws + cur + (mrow) * 32 + quad * 8);
        short8 b1 = *(const short8*)(Ws + cur + (16 + mrow) * 32 + quad * 8);
        short8 b2 = *(const short8*)(Ws + cur + (32 + mrow) * 32 + quad * 8);
        short8 b3 = *(const short8*)(Ws + cur + (48 + mrow) * 32 + quad * 8);
        acc0 = __builtin_amdgcn_mfma_f32_16x16x32_bf16(av, b0, acc0, 0, 0, 0);
        acc1 = __builtin_amdgcn_mfma_f32_16x16x32_bf16(av, b1, acc1, 0, 0, 0);
        acc2 = __builtin_amdgcn_mfma_f32_16x16x32_bf16(av, b2, acc2, 0, 0, 0);
        acc3 = __builtin_amdgcn_mfma_f32_16x16x32_bf16(av, b3, acc3, 0, 0, 0);
        __syncthreads();   // drains prefetch vmcnt + protects LDS reuse
    }

    f32x4 accs[4] = {acc0, acc1, acc2, acc3};
    #pragma unroll
    for (int ct = 0; ct < 4; ++ct) {
        int col = bn + ct * 16 + mrow;
        float bv = bias ? bias[col] : 0.0f;
        #pragma unroll
        for (int rg = 0; rg < 4; ++rg) {
            int rw = bm + wv * 16 + quad * 4 + rg;   // C/D: col=lane&15, row=quad*4+reg
            float val = accs[ct][rg] + bv;
            if (outF) outF[(size_t)rw * N + col] = val;
            else      outB[(size_t)rw * N + col] = f2bf(val);
        }
    }
}

// ---------------- fused projections: 4 segments, 576 blocks -----------------
// [0,96):    wq = inputs @ Wq^T                      -> bf16 [768][512]
// [96,288):  uh = mems @ Wc^T + bc                   -> bf16 [1536][512]
// [288,480): M2 = mems @ WoutC^T (Wout cols 0:512)   -> bf16 [1536][512]
// [480,576): ih = inputs @ WoutI^T + bout (512:1024) -> fp32 [768][512]
__global__ __launch_bounds__(256) void proj_gemm(
    const unsigned short* __restrict__ inputs_bf,
    const unsigned short* __restrict__ mems_bf,
    const unsigned short* __restrict__ Wq_bf,
    const unsigned short* __restrict__ Wc_bf,
    const float* __restrict__ bc,
    const unsigned short* __restrict__ Wout_bf,
    const float* __restrict__ bout,
    unsigned short* __restrict__ wq_o, unsigned short* __restrict__ uh_o,
    unsigned short* __restrict__ m2_o, float* __restrict__ ih_o)
{
    __shared__ __align__(16) unsigned short As[2 * 2048];
    __shared__ __align__(16) unsigned short Ws[2 * 2048];
    int bid = blockIdx.x;
    if (bid < 96) {
        gemm_tile(As, Ws, inputs_bf, DIN, Wq_bf, DIN, nullptr, nullptr, wq_o,
                  (bid >> 3) * 64, (bid & 7) * 64, DM, DIN);
    } else if (bid < 288) {
        bid -= 96;
        gemm_tile(As, Ws, mems_bf, DM, Wc_bf, DM, bc, nullptr, uh_o,
                  (bid >> 3) * 64, (bid & 7) * 64, DM, DM);
    } else if (bid < 480) {
        bid -= 288;
        gemm_tile(As, Ws, mems_bf, DM, Wout_bf, DM + DIN, nullptr, nullptr, m2_o,
                  (bid >> 3) * 64, (bid & 7) * 64, DM, DM);
    } else {
        bid -= 480;
        gemm_tile(As, Ws, inputs_bf, DIN, Wout_bf + DM, DM + DIN, bout, ih_o, nullptr,
                  (bid >> 3) * 64, (bid & 7) * 64, DIN, DIN);
    }
}

// ---------------- fused scores + softmax + context(M2) + ih add -------------
// one block per (b,t). Scores: wave wid owns s = wid,wid+4,...
// Context: attn_h[row] = inv * sum_s e_s * M2[b,s,:] + ih[row,:]
//   wave wid owns s in [wid*48,(wid+1)*48); lane owns dims lane*8..+8
//   -> 48 independent coalesced 1KB row loads per wave, LDS cross-wave reduce.
__global__ __launch_bounds__(256) void attn_core(
    const unsigned short* __restrict__ wq,     // [B*T][DM] bf16
    const unsigned short* __restrict__ uh,     // [B*S][DM] bf16
    const float* __restrict__ v,               // [DM] fp32
    const unsigned short* __restrict__ m2,     // [B*S][DM] bf16
    const float* __restrict__ ih,              // [B*T][DIN] fp32 (incl bout)
    const int* __restrict__ masks,             // [B]
    float* __restrict__ align_out,             // [B*T][S] fp32
    float* __restrict__ attn_h)                // [B*T][DIN] fp32
{
    __shared__ float s_align[SS];
    __shared__ __align__(16) float s_part[4][DM];
    __shared__ float s_stat;
    const int row = blockIdx.x, b = row / TT;
    const int tid = threadIdx.x, lane = tid & 63, wid = tid >> 6;
    const int len = masks[b];

    float qf[8], vf[8];
    {
        short8 q = *(const short8*)(wq + (size_t)row * DM + lane * 8);
        float4 v0 = *(const float4*)(v + lane * 8);
        float4 v1 = *(const float4*)(v + lane * 8 + 4);
        #pragma unroll
        for (int j = 0; j < 8; ++j) qf[j] = bf2f((unsigned short)q[j]);
        vf[0] = v0.x; vf[1] = v0.y; vf[2] = v0.z; vf[3] = v0.w;
        vf[4] = v1.x; vf[5] = v1.y; vf[6] = v1.z; vf[7] = v1.w;
    }

    for (int s = wid; s < SS; s += 4) {
        float val = -INFINITY;
        if (s < len) {
            short8 u = *(const short8*)(uh + ((size_t)b * SS + s) * DM + lane * 8);
            float part = 0.f;
            #pragma unroll
            for (int j = 0; j < 8; ++j) {
                float x = qf[j] + bf2f((unsigned short)u[j]);
                // exact tanh: 1 - 2/(exp2(x*2/ln2)+1)
                float e = __builtin_amdgcn_exp2f(x * 2.885390082f);
                float th = fmaf(-2.f, __builtin_amdgcn_rcpf(e + 1.f), 1.f);
                part = fmaf(vf[j], th, part);
            }
            #pragma unroll
            for (int off = 32; off; off >>= 1)
                part += __shfl_xor(part, off);
            val = part;
        }
        if (lane == 0) s_align[s] = val;
    }
    __syncthreads();

    if (tid < 64) {
        float m = fmaxf(fmaxf(s_align[tid], s_align[tid + 64]), s_align[tid + 128]);
        #pragma unroll
        for (int off = 32; off; off >>= 1) m = fmaxf(m, __shfl_xor(m, off));
        float e0 = __builtin_amdgcn_exp2f((s_align[tid]       - m) * 1.44269504f);
        float e1 = __builtin_amdgcn_exp2f((s_align[tid + 64]  - m) * 1.44269504f);
        float e2 = __builtin_amdgcn_exp2f((s_align[tid + 128] - m) * 1.44269504f);
        s_align[tid] = e0; s_align[tid + 64] = e1; s_align[tid + 128] = e2;
        float sum = e0 + e1 + e2;
        #pragma unroll
        for (int off = 32; off; off >>= 1) sum += __shfl_xor(sum, off);
        if (tid == 0) s_stat = 1.0f / sum;
    }
    __syncthreads();
    const float inv = s_stat;
    if (tid < SS) align_out[(size_t)row * SS + tid] = s_align[tid] * inv;

    // ---- context partials: wave wid covers s in [wid*48, wid*48+48) ----
    float accv[8] = {0,0,0,0,0,0,0,0};
    const unsigned short* m2b = m2 + ((size_t)b * SS + wid * 48) * DM + lane * 8;
    #pragma unroll 8
    for (int i = 0; i < 48; ++i) {
        float p = s_align[wid * 48 + i];           // e_s (0 for masked s)
        short8 mv = *(const short8*)(m2b + (size_t)i * DM);
        #pragma unroll
        for (int j = 0; j < 8; ++j)
            accv[j] = fmaf(p, bf2f((unsigned short)mv[j]), accv[j]);
    }
    {
        float4 t0; t0.x = accv[0]; t0.y = accv[1]; t0.z = accv[2]; t0.w = accv[3];
        float4 t1; t1.x = accv[4]; t1.y = accv[5]; t1.z = accv[6]; t1.w = accv[7];
        *(float4*)&s_part[wid][lane * 8]     = t0;
        *(float4*)&s_part[wid][lane * 8 + 4] = t1;
    }
    __syncthreads();

    // ---- cross-wave reduce + ih add: thread owns dims 2*tid, 2*tid+1 ----
    const int d0 = tid * 2;
    float r0 = s_part[0][d0]     + s_part[1][d0]     + s_part[2][d0]     + s_part[3][d0];
    float r1 = s_part[0][d0 + 1] + s_part[1][d0 + 1] + s_part[2][d0 + 1] + s_part[3][d0 + 1];
    float2 ihv = *(const float2*)(ih + (size_t)row * DIN + d0);
    float2 o;
    o.x = fmaf(r0, inv, ihv.x);
    o.y = fmaf(r1, inv, ihv.y);
    *(float2*)(attn_h + (size_t)row * DIN + d0) = o;
}

extern "C" void kernel_launch(void* const* d_in, const int* in_sizes, int n_in,
                              void* d_out, int out_size, void* d_ws, size_t ws_size,
                              hipStream_t stream) {
    (void)in_sizes; (void)n_in; (void)out_size; (void)ws_size;
    const float* inputs = (const float*)d_in[0];
    const float* mems   = (const float*)d_in[1];
    const int*   masks  = (const int*)  d_in[2];
    const float* Wq     = (const float*)d_in[3];
    const float* Wc     = (const float*)d_in[4];
    const float* bc     = (const float*)d_in[5];
    const float* v      = (const float*)d_in[6];
    const float* Wout   = (const float*)d_in[7];
    const float* bout   = (const float*)d_in[8];

    unsigned short* p = (unsigned short*)d_ws;
    unsigned short* inputs_bf = p;        p += 393216;   // B*T*DIN
    unsigned short* mems_bf   = p;        p += 786432;   // B*S*DM
    unsigned short* Wq_bf     = p;        p += 262144;
    unsigned short* Wc_bf     = p;        p += 262144;
    unsigned short* Wout_bf   = p;        p += 524288;
    unsigned short* uh_bf     = p;        p += 786432;
    unsigned short* wq_bf     = p;        p += 393216;
    unsigned short* m2_bf     = p;        p += 786432;
    float* ih                 = (float*)p;               // [768][512] fp32, 16B-aligned

    float* attn_h    = (float*)d_out;                    // [768][512]
    float* align_out = attn_h + (size_t)BB * TT * DIN;   // [768][192]

    prep_cvt<<<1088, 256, 0, stream>>>(inputs, mems, Wq, Wc, Wout,
                                       inputs_bf, mems_bf, Wq_bf, Wc_bf, Wout_bf);
    proj_gemm<<<576, 256, 0, stream>>>(inputs_bf, mems_bf, Wq_bf, Wc_bf, bc,
                                       Wout_bf, bout, wq_bf, uh_bf, m2_bf, ih);
    attn_core<<<BB * TT, 256, 0, stream>>>(wq_bf, uh_bf, v, m2_bf, ih, masks,
                                           align_out, attn_h);
}

// Round 6
// 117.621 us; speedup vs baseline: 1.4438x; 1.0151x over previous
//
#include <hip/hip_runtime.h>
#include <math.h>

#define BB 8
#define TT 96
#define SS 192
#define DIN 512
#define DM 512

typedef short short8 __attribute__((ext_vector_type(8)));
typedef float f32x4 __attribute__((ext_vector_type(4)));

__device__ __forceinline__ unsigned short f2bf(float f) {
    unsigned int u = __float_as_uint(f);
    unsigned int r = u + 0x7FFFu + ((u >> 16) & 1u);   // RNE
    return (unsigned short)(r >> 16);
}
__device__ __forceinline__ float bf2f(unsigned short h) {
    return __uint_as_float(((unsigned int)h) << 16);
}

__device__ __forceinline__ void load_lds16(const void* g, void* l) {
    __builtin_amdgcn_global_load_lds((__attribute__((address_space(1))) void*)g,
                                     (__attribute__((address_space(3))) void*)l,
                                     16, 0, 0);
}

// ---------------- prep: fp32 -> bf16 conversion of 5 arrays ----------------
// sizes: inputs 393216, mems 786432, Wq 262144, Wc 262144, Wout 524288
// blocks (2048 elems each): 192, 384, 128, 128, 256 ; cum 192,576,704,832,1088
__global__ __launch_bounds__(256) void prep_cvt(
    const float* __restrict__ s0, const float* __restrict__ s1,
    const float* __restrict__ s2, const float* __restrict__ s3,
    const float* __restrict__ s4,
    unsigned short* __restrict__ d0, unsigned short* __restrict__ d1,
    unsigned short* __restrict__ d2, unsigned short* __restrict__ d3,
    unsigned short* __restrict__ d4)
{
    int bid = blockIdx.x;
    const float* s; unsigned short* d; int base;
    if (bid < 192)      { s = s0; d = d0; base = bid * 2048; }
    else if (bid < 576) { s = s1; d = d1; base = (bid - 192) * 2048; }
    else if (bid < 704) { s = s2; d = d2; base = (bid - 576) * 2048; }
    else if (bid < 832) { s = s3; d = d3; base = (bid - 704) * 2048; }
    else                { s = s4; d = d4; base = (bid - 832) * 2048; }
    int idx = base + threadIdx.x * 8;
    float4 a = *(const float4*)(s + idx);
    float4 b = *(const float4*)(s + idx + 4);
    short8 o;
    o[0] = (short)f2bf(a.x); o[1] = (short)f2bf(a.y);
    o[2] = (short)f2bf(a.z); o[3] = (short)f2bf(a.w);
    o[4] = (short)f2bf(b.x); o[5] = (short)f2bf(b.y);
    o[6] = (short)f2bf(b.z); o[7] = (short)f2bf(b.w);
    *(short8*)(d + idx) = o;
}

// ---------------- bf16 MFMA GEMM tile: triple-buffered counted-vmcnt --------
// out[m][n] = sum_k A[m][k]*W[n][k] ; 64x64 tile, 256 threads (4 waves),
// K-chunk 32, 3 LDS buffers, prefetch depth 2, global_load_lds width=16.
// Counted s_waitcnt vmcnt(4) keeps the 2-ahead prefetch in flight across the
// barrier (T4 discipline) instead of __syncthreads' vmcnt(0) drain per chunk.
__device__ __forceinline__ void gemm_tile(
    unsigned short* As, unsigned short* Ws,   // shared, 3*2048 ushorts each
    const unsigned short* __restrict__ A, int lda,
    const unsigned short* __restrict__ W, int ldw,
    const float* __restrict__ bias,
    float* __restrict__ outF, unsigned short* __restrict__ outB,
    int bm, int bn, int N, int K)
{
    const int tid = threadIdx.x;
    const int r  = tid >> 2;          // 0..63 : tile row loaded by this thread
    const int kc = (tid & 3) * 8;     // k-offset within chunk
    const int lane = tid & 63, wv = tid >> 6;
    const int quad = lane >> 4, mrow = lane & 15;

    f32x4 acc0 = {0,0,0,0}, acc1 = {0,0,0,0}, acc2 = {0,0,0,0}, acc3 = {0,0,0,0};

    const unsigned short* arow = A + (size_t)(bm + r) * lda;
    const unsigned short* wrow = W + (size_t)(bn + r) * ldw;

    // prologue: stage chunks 0,1 into buffers 0,1  (K=512 -> NC=16 >= 2 always)
    load_lds16(arow + kc,      As + tid * 8);
    load_lds16(wrow + kc,      Ws + tid * 8);
    load_lds16(arow + 32 + kc, As + 2048 + tid * 8);
    load_lds16(wrow + 32 + kc, Ws + 2048 + tid * 8);

    const int NC = K >> 5;
    int cur = 0;
    for (int c = 0; c < NC; ++c) {
        if (c + 2 < NC) {
            int nb = cur + 2; if (nb >= 3) nb -= 3;
            int gk = ((c + 2) << 5) + kc;
            load_lds16(arow + gk, As + nb * 2048 + tid * 8);
            load_lds16(wrow + gk, Ws + nb * 2048 + tid * 8);
            // my chunk-c loads done; chunks c+1,c+2 (4 loads) stay in flight
            asm volatile("s_waitcnt vmcnt(4)" ::: "memory");
        } else if (c + 1 < NC) {
            asm volatile("s_waitcnt vmcnt(2)" ::: "memory");
        } else {
            asm volatile("s_waitcnt vmcnt(0)" ::: "memory");
        }
        __builtin_amdgcn_s_barrier();          // everyone's chunk-c LDS ready
        __builtin_amdgcn_sched_barrier(0);     // keep ds_reads below barrier
        const unsigned short* Ab = As + cur * 2048;
        const unsigned short* Wb = Ws + cur * 2048;
        short8 av = *(const short8*)(Ab + (wv * 16 + mrow) * 32 + quad * 8);
        short8 b0 = *(const short8*)(Wb + (mrow) * 32 + quad * 8);
        short8 b1 = *(const short8*)(Wb + (16 + mrow) * 32 + quad * 8);
        short8 b2 = *(const short8*)(Wb + (32 + mrow) * 32 + quad * 8);
        short8 b3 = *(const short8*)(Wb + (48 + mrow) * 32 + quad * 8);
        acc0 = __builtin_amdgcn_mfma_f32_16x16x32_bf16(av, b0, acc0, 0, 0, 0);
        acc1 = __builtin_amdgcn_mfma_f32_16x16x32_bf16(av, b1, acc1, 0, 0, 0);
        acc2 = __builtin_amdgcn_mfma_f32_16x16x32_bf16(av, b2, acc2, 0, 0, 0);
        acc3 = __builtin_amdgcn_mfma_f32_16x16x32_bf16(av, b3, acc3, 0, 0, 0);
        __builtin_amdgcn_sched_barrier(0);     // reads complete before barrier
        __builtin_amdgcn_s_barrier();          // safe to overwrite buf (c+2)%3
        cur += 1; if (cur >= 3) cur -= 3;
    }

    f32x4 accs[4] = {acc0, acc1, acc2, acc3};
    #pragma unroll
    for (int ct = 0; ct < 4; ++ct) {
        int col = bn + ct * 16 + mrow;
        float bv = bias ? bias[col] : 0.0f;
        #pragma unroll
        for (int rg = 0; rg < 4; ++rg) {
            int rw = bm + wv * 16 + quad * 4 + rg;   // C/D: col=lane&15, row=quad*4+reg
            float val = accs[ct][rg] + bv;
            if (outF) outF[(size_t)rw * N + col] = val;
            else      outB[(size_t)rw * N + col] = f2bf(val);
        }
    }
}

// ---------------- fused projections: 4 segments, 576 blocks -----------------
// [0,96):    wq = inputs @ Wq^T                      -> bf16 [768][512]
// [96,288):  uh = mems @ Wc^T + bc                   -> bf16 [1536][512]
// [288,480): M2 = mems @ WoutC^T (Wout cols 0:512)   -> bf16 [1536][512]
// [480,576): ih = inputs @ WoutI^T + bout (512:1024) -> fp32 [768][512]
__global__ __launch_bounds__(256) void proj_gemm(
    const unsigned short* __restrict__ inputs_bf,
    const unsigned short* __restrict__ mems_bf,
    const unsigned short* __restrict__ Wq_bf,
    const unsigned short* __restrict__ Wc_bf,
    const float* __restrict__ bc,
    const unsigned short* __restrict__ Wout_bf,
    const float* __restrict__ bout,
    unsigned short* __restrict__ wq_o, unsigned short* __restrict__ uh_o,
    unsigned short* __restrict__ m2_o, float* __restrict__ ih_o)
{
    __shared__ __align__(16) unsigned short As[3 * 2048];
    __shared__ __align__(16) unsigned short Ws[3 * 2048];
    int bid = blockIdx.x;
    if (bid < 96) {
        gemm_tile(As, Ws, inputs_bf, DIN, Wq_bf, DIN, nullptr, nullptr, wq_o,
                  (bid >> 3) * 64, (bid & 7) * 64, DM, DIN);
    } else if (bid < 288) {
        bid -= 96;
        gemm_tile(As, Ws, mems_bf, DM, Wc_bf, DM, bc, nullptr, uh_o,
                  (bid >> 3) * 64, (bid & 7) * 64, DM, DM);
    } else if (bid < 480) {
        bid -= 288;
        gemm_tile(As, Ws, mems_bf, DM, Wout_bf, DM + DIN, nullptr, nullptr, m2_o,
                  (bid >> 3) * 64, (bid & 7) * 64, DM, DM);
    } else {
        bid -= 480;
        gemm_tile(As, Ws, inputs_bf, DIN, Wout_bf + DM, DM + DIN, bout, ih_o, nullptr,
                  (bid >> 3) * 64, (bid & 7) * 64, DIN, DIN);
    }
}

// ---------------- fused scores + softmax + context(M2) + ih add -------------
// one block per (b,t). Scores: wave wid owns s = wid,wid+4,...
// Context: attn_h[row] = inv * sum_s e_s * M2[b,s,:] + ih[row,:]
//   wave wid owns s in [wid*48,(wid+1)*48); lane owns dims lane*8..+8
//   -> 48 independent coalesced 1KB row loads per wave, LDS cross-wave reduce.
__global__ __launch_bounds__(256) void attn_core(
    const unsigned short* __restrict__ wq,     // [B*T][DM] bf16
    const unsigned short* __restrict__ uh,     // [B*S][DM] bf16
    const float* __restrict__ v,               // [DM] fp32
    const unsigned short* __restrict__ m2,     // [B*S][DM] bf16
    const float* __restrict__ ih,              // [B*T][DIN] fp32 (incl bout)
    const int* __restrict__ masks,             // [B]
    float* __restrict__ align_out,             // [B*T][S] fp32
    float* __restrict__ attn_h)                // [B*T][DIN] fp32
{
    __shared__ float s_align[SS];
    __shared__ __align__(16) float s_part[4][DM];
    __shared__ float s_stat;
    const int row = blockIdx.x, b = row / TT;
    const int tid = threadIdx.x, lane = tid & 63, wid = tid >> 6;
    const int len = masks[b];

    float qf[8], vf[8];
    {
        short8 q = *(const short8*)(wq + (size_t)row * DM + lane * 8);
        float4 v0 = *(const float4*)(v + lane * 8);
        float4 v1 = *(const float4*)(v + lane * 8 + 4);
        #pragma unroll
        for (int j = 0; j < 8; ++j) qf[j] = bf2f((unsigned short)q[j]);
        vf[0] = v0.x; vf[1] = v0.y; vf[2] = v0.z; vf[3] = v0.w;
        vf[4] = v1.x; vf[5] = v1.y; vf[6] = v1.z; vf[7] = v1.w;
    }

    for (int s = wid; s < SS; s += 4) {
        float val = -INFINITY;
        if (s < len) {
            short8 u = *(const short8*)(uh + ((size_t)b * SS + s) * DM + lane * 8);
            float part = 0.f;
            #pragma unroll
            for (int j = 0; j < 8; ++j) {
                float x = qf[j] + bf2f((unsigned short)u[j]);
                // exact tanh: 1 - 2/(exp2(x*2/ln2)+1)
                float e = __builtin_amdgcn_exp2f(x * 2.885390082f);
                float th = fmaf(-2.f, __builtin_amdgcn_rcpf(e + 1.f), 1.f);
                part = fmaf(vf[j], th, part);
            }
            #pragma unroll
            for (int off = 32; off; off >>= 1)
                part += __shfl_xor(part, off);
            val = part;
        }
        if (lane == 0) s_align[s] = val;
    }
    __syncthreads();

    if (tid < 64) {
        float m = fmaxf(fmaxf(s_align[tid], s_align[tid + 64]), s_align[tid + 128]);
        #pragma unroll
        for (int off = 32; off; off >>= 1) m = fmaxf(m, __shfl_xor(m, off));
        float e0 = __builtin_amdgcn_exp2f((s_align[tid]       - m) * 1.44269504f);
        float e1 = __builtin_amdgcn_exp2f((s_align[tid + 64]  - m) * 1.44269504f);
        float e2 = __builtin_amdgcn_exp2f((s_align[tid + 128] - m) * 1.44269504f);
        s_align[tid] = e0; s_align[tid + 64] = e1; s_align[tid + 128] = e2;
        float sum = e0 + e1 + e2;
        #pragma unroll
        for (int off = 32; off; off >>= 1) sum += __shfl_xor(sum, off);
        if (tid == 0) s_stat = 1.0f / sum;
    }
    __syncthreads();
    const float inv = s_stat;
    if (tid < SS) align_out[(size_t)row * SS + tid] = s_align[tid] * inv;

    // ---- context partials: wave wid covers s in [wid*48, wid*48+48) ----
    float accv[8] = {0,0,0,0,0,0,0,0};
    const unsigned short* m2b = m2 + ((size_t)b * SS + wid * 48) * DM + lane * 8;
    #pragma unroll 8
    for (int i = 0; i < 48; ++i) {
        float p = s_align[wid * 48 + i];           // e_s (0 for masked s)
        short8 mv = *(const short8*)(m2b + (size_t)i * DM);
        #pragma unroll
        for (int j = 0; j < 8; ++j)
            accv[j] = fmaf(p, bf2f((unsigned short)mv[j]), accv[j]);
    }
    {
        float4 t0; t0.x = accv[0]; t0.y = accv[1]; t0.z = accv[2]; t0.w = accv[3];
        float4 t1; t1.x = accv[4]; t1.y = accv[5]; t1.z = accv[6]; t1.w = accv[7];
        *(float4*)&s_part[wid][lane * 8]     = t0;
        *(float4*)&s_part[wid][lane * 8 + 4] = t1;
    }
    __syncthreads();

    // ---- cross-wave reduce + ih add: thread owns dims 2*tid, 2*tid+1 ----
    const int d0 = tid * 2;
    float r0 = s_part[0][d0]     + s_part[1][d0]     + s_part[2][d0]     + s_part[3][d0];
    float r1 = s_part[0][d0 + 1] + s_part[1][d0 + 1] + s_part[2][d0 + 1] + s_part[3][d0 + 1];
    float2 ihv = *(const float2*)(ih + (size_t)row * DIN + d0);
    float2 o;
    o.x = fmaf(r0, inv, ihv.x);
    o.y = fmaf(r1, inv, ihv.y);
    *(float2*)(attn_h + (size_t)row * DIN + d0) = o;
}

extern "C" void kernel_launch(void* const* d_in, const int* in_sizes, int n_in,
                              void* d_out, int out_size, void* d_ws, size_t ws_size,
                              hipStream_t stream) {
    (void)in_sizes; (void)n_in; (void)out_size; (void)ws_size;
    const float* inputs = (const float*)d_in[0];
    const float* mems   = (const float*)d_in[1];
    const int*   masks  = (const int*)  d_in[2];
    const float* Wq     = (const float*)d_in[3];
    const float* Wc     = (const float*)d_in[4];
    const float* bc     = (const float*)d_in[5];
    const float* v      = (const float*)d_in[6];
    const float* Wout   = (const float*)d_in[7];
    const float* bout   = (const float*)d_in[8];

    unsigned short* p = (unsigned short*)d_ws;
    unsigned short* inputs_bf = p;        p += 393216;   // B*T*DIN
    unsigned short* mems_bf   = p;        p += 786432;   // B*S*DM
    unsigned short* Wq_bf     = p;        p += 262144;
    unsigned short* Wc_bf     = p;        p += 262144;
    unsigned short* Wout_bf   = p;        p += 524288;
    unsigned short* uh_bf     = p;        p += 786432;
    unsigned short* wq_bf     = p;        p += 393216;
    unsigned short* m2_bf     = p;        p += 786432;
    float* ih                 = (float*)p;               // [768][512] fp32, 16B-aligned

    float* attn_h    = (float*)d_out;                    // [768][512]
    float* align_out = attn_h + (size_t)BB * TT * DIN;   // [768][192]

    prep_cvt<<<1088, 256, 0, stream>>>(inputs, mems, Wq, Wc, Wout,
                                       inputs_bf, mems_bf, Wq_bf, Wc_bf, Wout_bf);
    proj_gemm<<<576, 256, 0, stream>>>(inputs_bf, mems_bf, Wq_bf, Wc_bf, bc,
                                       Wout_bf, bout, wq_bf, uh_bf, m2_bf, ih);
    attn_core<<<BB * TT, 256, 0, stream>>>(wq_bf, uh_bf, v, m2_bf, ih, masks,
                                           align_out, attn_h);
}

// Round 7
// 115.218 us; speedup vs baseline: 1.4739x; 1.0209x over previous
//
#include <hip/hip_runtime.h>
#include <math.h>

#define BB 8
#define TT 96
#define SS 192
#define DIN 512
#define DM 512

typedef short short8 __attribute__((ext_vector_type(8)));
typedef float f32x4 __attribute__((ext_vector_type(4)));

__device__ __forceinline__ unsigned short f2bf(float f) {
    unsigned int u = __float_as_uint(f);
    unsigned int r = u + 0x7FFFu + ((u >> 16) & 1u);   // RNE
    return (unsigned short)(r >> 16);
}
__device__ __forceinline__ float bf2f(unsigned short h) {
    return __uint_as_float(((unsigned int)h) << 16);
}

__device__ __forceinline__ void load_lds16(const void* g, void* l) {
    __builtin_amdgcn_global_load_lds((__attribute__((address_space(1))) void*)g,
                                     (__attribute__((address_space(3))) void*)l,
                                     16, 0, 0);
}

// ---------------- prep: fp32 -> bf16 conversion of 5 arrays ----------------
// sizes: inputs 393216, mems 786432, Wq 262144, Wc 262144, Wout 524288
// blocks (2048 elems each): 192, 384, 128, 128, 256 ; cum 192,576,704,832,1088
__global__ __launch_bounds__(256) void prep_cvt(
    const float* __restrict__ s0, const float* __restrict__ s1,
    const float* __restrict__ s2, const float* __restrict__ s3,
    const float* __restrict__ s4,
    unsigned short* __restrict__ d0, unsigned short* __restrict__ d1,
    unsigned short* __restrict__ d2, unsigned short* __restrict__ d3,
    unsigned short* __restrict__ d4)
{
    int bid = blockIdx.x;
    const float* s; unsigned short* d; int base;
    if (bid < 192)      { s = s0; d = d0; base = bid * 2048; }
    else if (bid < 576) { s = s1; d = d1; base = (bid - 192) * 2048; }
    else if (bid < 704) { s = s2; d = d2; base = (bid - 576) * 2048; }
    else if (bid < 832) { s = s3; d = d3; base = (bid - 704) * 2048; }
    else                { s = s4; d = d4; base = (bid - 832) * 2048; }
    int idx = base + threadIdx.x * 8;
    float4 a = *(const float4*)(s + idx);
    float4 b = *(const float4*)(s + idx + 4);
    short8 o;
    o[0] = (short)f2bf(a.x); o[1] = (short)f2bf(a.y);
    o[2] = (short)f2bf(a.z); o[3] = (short)f2bf(a.w);
    o[4] = (short)f2bf(b.x); o[5] = (short)f2bf(b.y);
    o[6] = (short)f2bf(b.z); o[7] = (short)f2bf(b.w);
    *(short8*)(d + idx) = o;
}

// ---------------- bf16 MFMA GEMM tile: triple-buffered counted-vmcnt --------
// out[m][n] = sum_k A[m][k]*W[n][k] ; 64x64 tile, 256 threads (4 waves),
// K-chunk 32, 3 LDS buffers, prefetch depth 2, global_load_lds width=16.
__device__ __forceinline__ void gemm_tile(
    unsigned short* As, unsigned short* Ws,   // shared, 3*2048 ushorts each
    const unsigned short* __restrict__ A, int lda,
    const unsigned short* __restrict__ W, int ldw,
    const float* __restrict__ bias,
    float* __restrict__ outF, unsigned short* __restrict__ outB,
    int bm, int bn, int N, int K)
{
    const int tid = threadIdx.x;
    const int r  = tid >> 2;          // 0..63 : tile row loaded by this thread
    const int kc = (tid & 3) * 8;     // k-offset within chunk
    const int lane = tid & 63, wv = tid >> 6;
    const int quad = lane >> 4, mrow = lane & 15;

    f32x4 acc0 = {0,0,0,0}, acc1 = {0,0,0,0}, acc2 = {0,0,0,0}, acc3 = {0,0,0,0};

    const unsigned short* arow = A + (size_t)(bm + r) * lda;
    const unsigned short* wrow = W + (size_t)(bn + r) * ldw;

    // prologue: stage chunks 0,1 into buffers 0,1  (K=512 -> NC=16 >= 2 always)
    load_lds16(arow + kc,      As + tid * 8);
    load_lds16(wrow + kc,      Ws + tid * 8);
    load_lds16(arow + 32 + kc, As + 2048 + tid * 8);
    load_lds16(wrow + 32 + kc, Ws + 2048 + tid * 8);

    const int NC = K >> 5;
    int cur = 0;
    for (int c = 0; c < NC; ++c) {
        if (c + 2 < NC) {
            int nb = cur + 2; if (nb >= 3) nb -= 3;
            int gk = ((c + 2) << 5) + kc;
            load_lds16(arow + gk, As + nb * 2048 + tid * 8);
            load_lds16(wrow + gk, Ws + nb * 2048 + tid * 8);
            // my chunk-c loads done; chunks c+1,c+2 (4 loads) stay in flight
            asm volatile("s_waitcnt vmcnt(4)" ::: "memory");
        } else if (c + 1 < NC) {
            asm volatile("s_waitcnt vmcnt(2)" ::: "memory");
        } else {
            asm volatile("s_waitcnt vmcnt(0)" ::: "memory");
        }
        __builtin_amdgcn_s_barrier();          // everyone's chunk-c LDS ready
        __builtin_amdgcn_sched_barrier(0);     // keep ds_reads below barrier
        const unsigned short* Ab = As + cur * 2048;
        const unsigned short* Wb = Ws + cur * 2048;
        short8 av = *(const short8*)(Ab + (wv * 16 + mrow) * 32 + quad * 8);
        short8 b0 = *(const short8*)(Wb + (mrow) * 32 + quad * 8);
        short8 b1 = *(const short8*)(Wb + (16 + mrow) * 32 + quad * 8);
        short8 b2 = *(const short8*)(Wb + (32 + mrow) * 32 + quad * 8);
        short8 b3 = *(const short8*)(Wb + (48 + mrow) * 32 + quad * 8);
        acc0 = __builtin_amdgcn_mfma_f32_16x16x32_bf16(av, b0, acc0, 0, 0, 0);
        acc1 = __builtin_amdgcn_mfma_f32_16x16x32_bf16(av, b1, acc1, 0, 0, 0);
        acc2 = __builtin_amdgcn_mfma_f32_16x16x32_bf16(av, b2, acc2, 0, 0, 0);
        acc3 = __builtin_amdgcn_mfma_f32_16x16x32_bf16(av, b3, acc3, 0, 0, 0);
        __builtin_amdgcn_sched_barrier(0);     // reads complete before barrier
        __builtin_amdgcn_s_barrier();          // safe to overwrite buf (c+2)%3
        cur += 1; if (cur >= 3) cur -= 3;
    }

    f32x4 accs[4] = {acc0, acc1, acc2, acc3};
    #pragma unroll
    for (int ct = 0; ct < 4; ++ct) {
        int col = bn + ct * 16 + mrow;
        float bv = bias ? bias[col] : 0.0f;
        #pragma unroll
        for (int rg = 0; rg < 4; ++rg) {
            int rw = bm + wv * 16 + quad * 4 + rg;   // C/D: col=lane&15, row=quad*4+reg
            float val = accs[ct][rg] + bv;
            if (outF) outF[(size_t)rw * N + col] = val;
            else      outB[(size_t)rw * N + col] = f2bf(val);
        }
    }
}

// ---------------- fused projections: 4 segments, 576 blocks -----------------
// [0,96):    wq = inputs @ Wq^T                      -> bf16 [768][512]
// [96,288):  uh = mems @ Wc^T + bc                   -> bf16 [1536][512]
// [288,480): M2 = mems @ WoutC^T (Wout cols 0:512)   -> bf16 [1536][512]
// [480,576): ih = inputs @ WoutI^T + bout (512:1024) -> fp32 [768][512]
__global__ __launch_bounds__(256) void proj_gemm(
    const unsigned short* __restrict__ inputs_bf,
    const unsigned short* __restrict__ mems_bf,
    const unsigned short* __restrict__ Wq_bf,
    const unsigned short* __restrict__ Wc_bf,
    const float* __restrict__ bc,
    const unsigned short* __restrict__ Wout_bf,
    const float* __restrict__ bout,
    unsigned short* __restrict__ wq_o, unsigned short* __restrict__ uh_o,
    unsigned short* __restrict__ m2_o, float* __restrict__ ih_o)
{
    __shared__ __align__(16) unsigned short As[3 * 2048];
    __shared__ __align__(16) unsigned short Ws[3 * 2048];
    int bid = blockIdx.x;
    if (bid < 96) {
        gemm_tile(As, Ws, inputs_bf, DIN, Wq_bf, DIN, nullptr, nullptr, wq_o,
                  (bid >> 3) * 64, (bid & 7) * 64, DM, DIN);
    } else if (bid < 288) {
        bid -= 96;
        gemm_tile(As, Ws, mems_bf, DM, Wc_bf, DM, bc, nullptr, uh_o,
                  (bid >> 3) * 64, (bid & 7) * 64, DM, DM);
    } else if (bid < 480) {
        bid -= 288;
        gemm_tile(As, Ws, mems_bf, DM, Wout_bf, DM + DIN, nullptr, nullptr, m2_o,
                  (bid >> 3) * 64, (bid & 7) * 64, DM, DM);
    } else {
        bid -= 480;
        gemm_tile(As, Ws, inputs_bf, DIN, Wout_bf + DM, DM + DIN, bout, ih_o, nullptr,
                  (bid >> 3) * 64, (bid & 7) * 64, DIN, DIN);
    }
}

// ---------------- fused scores + softmax + context(M2) + ih add -------------
// one block per (b,t). score = SV - 2*sum_m v_m/(exp2(C(q+u))+1)  (C=2/ln2)
// SV = sum_m v_m reduced ONCE per block; per-dim cost 6 instrs (was 8).
// Scores loop runs s<len only (masked tail pre-set to -INF, disjoint writers).
// Context loop per wave bounded by len (masked rows have e_s=0, skip loads).
__global__ __launch_bounds__(256) void attn_core(
    const unsigned short* __restrict__ wq,     // [B*T][DM] bf16
    const unsigned short* __restrict__ uh,     // [B*S][DM] bf16
    const float* __restrict__ v,               // [DM] fp32
    const unsigned short* __restrict__ m2,     // [B*S][DM] bf16
    const float* __restrict__ ih,              // [B*T][DIN] fp32 (incl bout)
    const int* __restrict__ masks,             // [B]
    float* __restrict__ align_out,             // [B*T][S] fp32
    float* __restrict__ attn_h)                // [B*T][DIN] fp32
{
    __shared__ float s_align[SS];
    __shared__ __align__(16) float s_part[4][DM];
    __shared__ float s_stat;
    const int row = blockIdx.x, b = row / TT;
    const int tid = threadIdx.x, lane = tid & 63, wid = tid >> 6;
    const int len = masks[b];
    const float C = 2.885390082f;   // 2/ln2

    // masked tail of s_align -> -INF (writers disjoint from scores loop: s>=len)
    if (tid >= len && tid < SS) s_align[tid] = -INFINITY;

    float cqf[8], vf[8];
    {
        short8 q = *(const short8*)(wq + (size_t)row * DM + lane * 8);
        float4 v0 = *(const float4*)(v + lane * 8);
        float4 v1 = *(const float4*)(v + lane * 8 + 4);
        #pragma unroll
        for (int j = 0; j < 8; ++j) cqf[j] = bf2f((unsigned short)q[j]) * C;
        vf[0] = v0.x; vf[1] = v0.y; vf[2] = v0.z; vf[3] = v0.w;
        vf[4] = v1.x; vf[5] = v1.y; vf[6] = v1.z; vf[7] = v1.w;
    }
    // SV = sum over all 512 dims of v (block-constant), reduced once
    float SV = ((vf[0] + vf[1]) + (vf[2] + vf[3])) +
               ((vf[4] + vf[5]) + (vf[6] + vf[7]));
    #pragma unroll
    for (int off = 32; off; off >>= 1) SV += __shfl_xor(SV, off);

    #pragma unroll 2
    for (int s = wid; s < len; s += 4) {
        short8 u = *(const short8*)(uh + ((size_t)b * SS + s) * DM + lane * 8);
        float pr = 0.f;
        #pragma unroll
        for (int j = 0; j < 8; ++j) {
            float e = __builtin_amdgcn_exp2f(
                fmaf(bf2f((unsigned short)u[j]), C, cqf[j]));
            float rc = __builtin_amdgcn_rcpf(e + 1.f);
            pr = fmaf(vf[j], rc, pr);
        }
        #pragma unroll
        for (int off = 32; off; off >>= 1)
            pr += __shfl_xor(pr, off);
        if (lane == 0) s_align[s] = fmaf(-2.f, pr, SV);
    }
    __syncthreads();

    if (tid < 64) {
        float m = fmaxf(fmaxf(s_align[tid], s_align[tid + 64]), s_align[tid + 128]);
        #pragma unroll
        for (int off = 32; off; off >>= 1) m = fmaxf(m, __shfl_xor(m, off));
        float e0 = __builtin_amdgcn_exp2f((s_align[tid]       - m) * 1.44269504f);
        float e1 = __builtin_amdgcn_exp2f((s_align[tid + 64]  - m) * 1.44269504f);
        float e2 = __builtin_amdgcn_exp2f((s_align[tid + 128] - m) * 1.44269504f);
        s_align[tid] = e0; s_align[tid + 64] = e1; s_align[tid + 128] = e2;
        float sum = e0 + e1 + e2;
        #pragma unroll
        for (int off = 32; off; off >>= 1) sum += __shfl_xor(sum, off);
        if (tid == 0) s_stat = 1.0f / sum;
    }
    __syncthreads();
    const float inv = s_stat;
    if (tid < SS) align_out[(size_t)row * SS + tid] = s_align[tid] * inv;

    // ---- context partials: wave wid covers s in [wid*48, wid*48+nloc) ----
    // s >= len has e_s = 0: skip those loads entirely.
    const int sbase = wid * 48;
    int nloc = len - sbase;
    nloc = nloc < 0 ? 0 : (nloc > 48 ? 48 : nloc);
    float accv[8] = {0,0,0,0,0,0,0,0};
    const unsigned short* m2b = m2 + ((size_t)b * SS + sbase) * DM + lane * 8;
    #pragma unroll 4
    for (int i = 0; i < nloc; ++i) {
        float p = s_align[sbase + i];
        short8 mv = *(const short8*)(m2b + (size_t)i * DM);
        #pragma unroll
        for (int j = 0; j < 8; ++j)
            accv[j] = fmaf(p, bf2f((unsigned short)mv[j]), accv[j]);
    }
    {
        float4 t0; t0.x = accv[0]; t0.y = accv[1]; t0.z = accv[2]; t0.w = accv[3];
        float4 t1; t1.x = accv[4]; t1.y = accv[5]; t1.z = accv[6]; t1.w = accv[7];
        *(float4*)&s_part[wid][lane * 8]     = t0;
        *(float4*)&s_part[wid][lane * 8 + 4] = t1;
    }
    __syncthreads();

    // ---- cross-wave reduce + ih add: thread owns dims 2*tid, 2*tid+1 ----
    const int d0 = tid * 2;
    float r0 = s_part[0][d0]     + s_part[1][d0]     + s_part[2][d0]     + s_part[3][d0];
    float r1 = s_part[0][d0 + 1] + s_part[1][d0 + 1] + s_part[2][d0 + 1] + s_part[3][d0 + 1];
    float2 ihv = *(const float2*)(ih + (size_t)row * DIN + d0);
    float2 o;
    o.x = fmaf(r0, inv, ihv.x);
    o.y = fmaf(r1, inv, ihv.y);
    *(float2*)(attn_h + (size_t)row * DIN + d0) = o;
}

extern "C" void kernel_launch(void* const* d_in, const int* in_sizes, int n_in,
                              void* d_out, int out_size, void* d_ws, size_t ws_size,
                              hipStream_t stream) {
    (void)in_sizes; (void)n_in; (void)out_size; (void)ws_size;
    const float* inputs = (const float*)d_in[0];
    const float* mems   = (const float*)d_in[1];
    const int*   masks  = (const int*)  d_in[2];
    const float* Wq     = (const float*)d_in[3];
    const float* Wc     = (const float*)d_in[4];
    const float* bc     = (const float*)d_in[5];
    const float* v      = (const float*)d_in[6];
    const float* Wout   = (const float*)d_in[7];
    const float* bout   = (const float*)d_in[8];

    unsigned short* p = (unsigned short*)d_ws;
    unsigned short* inputs_bf = p;        p += 393216;   // B*T*DIN
    unsigned short* mems_bf   = p;        p += 786432;   // B*S*DM
    unsigned short* Wq_bf     = p;        p += 262144;
    unsigned short* Wc_bf     = p;        p += 262144;
    unsigned short* Wout_bf   = p;        p += 524288;
    unsigned short* uh_bf     = p;        p += 786432;
    unsigned short* wq_bf     = p;        p += 393216;
    unsigned short* m2_bf     = p;        p += 786432;
    float* ih                 = (float*)p;               // [768][512] fp32, 16B-aligned

    float* attn_h    = (float*)d_out;                    // [768][512]
    float* align_out = attn_h + (size_t)BB * TT * DIN;   // [768][192]

    prep_cvt<<<1088, 256, 0, stream>>>(inputs, mems, Wq, Wc, Wout,
                                       inputs_bf, mems_bf, Wq_bf, Wc_bf, Wout_bf);
    proj_gemm<<<576, 256, 0, stream>>>(inputs_bf, mems_bf, Wq_bf, Wc_bf, bc,
                                       Wout_bf, bout, wq_bf, uh_bf, m2_bf, ih);
    attn_core<<<BB * TT, 256, 0, stream>>>(wq_bf, uh_bf, v, m2_bf, ih, masks,
                                           align_out, attn_h);
}